// Round 2
// baseline (246.354 us; speedup 1.0000x reference)
//
#include <hip/hip_runtime.h>

#define B_   16
#define C_   96
#define N_   4096
#define BN_  65536
#define K_   16
#define E_   (BN_ * K_)

// ---------------------------------------------------------------------------
// Kernel A: transpose x [B, C, N] -> feats [BN, C]  (node-major rows, 384 B)
// ---------------------------------------------------------------------------
__global__ __launch_bounds__(256) void transpose_k(const float* __restrict__ x,
                                                   float* __restrict__ feats) {
    __shared__ float tile[32][65];  // +1 pad: conflict-free both phases
    int b  = blockIdx.z;
    int c0 = blockIdx.y * 32;
    int n0 = blockIdx.x * 64;
    const float* xp = x + (size_t)b * C_ * N_;
    // load: 32 c-rows x 64 n, coalesced along n
    for (int t = threadIdx.x; t < 32 * 64; t += 256) {
        int c = t >> 6, n = t & 63;
        tile[c][n] = xp[(size_t)(c0 + c) * N_ + n0 + n];
    }
    __syncthreads();
    // store: coalesced along c (32 consecutive floats per node)
    float* fp = feats + ((size_t)b * N_ + n0) * C_ + c0;
    for (int t = threadIdx.x; t < 32 * 64; t += 256) {
        int n = t >> 5, c = t & 31;
        fp[(size_t)n * C_ + c] = tile[c][n];
    }
}

// ---------------------------------------------------------------------------
// Kernel B: per-node max over 16 gathered rows, minus own row.
// 4 threads per node (interleaved float4 chunks r, r+4, ..., r+20),
// 64 nodes per 256-thread block. Gather reads are 64 B-contiguous per node.
// ---------------------------------------------------------------------------
__global__ __launch_bounds__(256) void gather_max_k(const float* __restrict__ feats,
                                                    const int* __restrict__ src,
                                                    float* __restrict__ agg) {
    int tid = threadIdx.x;
    int ln  = tid >> 2;          // local node 0..63
    int r   = tid & 3;           // chunk group 0..3
    size_t i = (size_t)blockIdx.x * 64 + ln;
    const int* s = src + i * K_;

    float4 m[6];
#pragma unroll
    for (int j = 0; j < 6; j++)
        m[j] = make_float4(-3.0e38f, -3.0e38f, -3.0e38f, -3.0e38f);

#pragma unroll
    for (int q = 0; q < 4; q++) {
        int4 iv = ((const int4*)s)[q];
        int ids[4] = {iv.x, iv.y, iv.z, iv.w};
#pragma unroll
        for (int kk = 0; kk < 4; kk++) {   // static indexing (no scratch)
            const float4* sr = (const float4*)(feats + (size_t)ids[kk] * C_);
#pragma unroll
            for (int j = 0; j < 6; j++) {
                float4 v = sr[r + 4 * j];
                m[j].x = fmaxf(m[j].x, v.x);
                m[j].y = fmaxf(m[j].y, v.y);
                m[j].z = fmaxf(m[j].z, v.z);
                m[j].w = fmaxf(m[j].w, v.w);
            }
        }
    }

    const float4* fr = (const float4*)(feats + i * C_);
    float4* ar = (float4*)(agg + i * C_);
#pragma unroll
    for (int j = 0; j < 6; j++) {
        float4 own = fr[r + 4 * j];
        ar[r + 4 * j] = make_float4(m[j].x - own.x, m[j].y - own.y,
                                    m[j].z - own.z, m[j].w - own.w);
    }
}

// ---------------------------------------------------------------------------
// Kernel C: out[b,o,n] = relu(bc[o] + sum_c W[o,2c]*x[b,c,n] + W[o,2c+1]*agg[i,c])
// Block: 256 threads (4 waves), tile = 64 consecutive nodes x all 96 outputs.
// Each wave owns 24 output rows, computed 8 at a time (register blocking).
// ---------------------------------------------------------------------------
__global__ __launch_bounds__(256) void conv_k(const float* __restrict__ x,
                                              const float* __restrict__ agg,
                                              const float* __restrict__ Wc,
                                              const float* __restrict__ bc,
                                              float* __restrict__ out) {
    __shared__ float xT[96][64];   // [c][n] — writes/reads conflict-free
    __shared__ float aT[96][65];   // +1 pad: transposed scatter writes
    int bidx = blockIdx.x;
    int b  = bidx >> 6;
    int n0 = (bidx & 63) << 6;

    const float* xp = x + (size_t)b * C_ * N_ + n0;
    for (int t = threadIdx.x; t < 96 * 16; t += 256) {
        int c = t >> 4, q = t & 15;
        float4 v = *(const float4*)(xp + (size_t)c * N_ + q * 4);
        xT[c][q * 4 + 0] = v.x; xT[c][q * 4 + 1] = v.y;
        xT[c][q * 4 + 2] = v.z; xT[c][q * 4 + 3] = v.w;
    }
    const float* ap = agg + ((size_t)b * N_ + n0) * C_;
    for (int t = threadIdx.x; t < 64 * 24; t += 256) {
        int n = t / 24, q = t % 24;
        float4 v = *(const float4*)(ap + (size_t)n * C_ + q * 4);
        aT[q * 4 + 0][n] = v.x; aT[q * 4 + 1][n] = v.y;
        aT[q * 4 + 2][n] = v.z; aT[q * 4 + 3][n] = v.w;
    }
    __syncthreads();

    int wave = threadIdx.x >> 6;
    int lane = threadIdx.x & 63;
    float* op = out + (size_t)b * C_ * N_ + n0 + lane;

#pragma unroll
    for (int g = 0; g < 3; g++) {
        int o0 = wave * 24 + g * 8;
        float acc[8];
#pragma unroll
        for (int u = 0; u < 8; u++) acc[u] = bc[o0 + u];
        for (int c = 0; c < 96; c++) {
            float xv = xT[c][lane];
            float av = aT[c][lane];
#pragma unroll
            for (int u = 0; u < 8; u++) {
                float2 w = *(const float2*)(Wc + (size_t)(o0 + u) * 192 + 2 * c);
                acc[u] += w.x * xv + w.y * av;
            }
        }
#pragma unroll
        for (int u = 0; u < 8; u++) {
            op[(size_t)(o0 + u) * N_] = fmaxf(acc[u], 0.0f);
        }
    }
}

// ---------------------------------------------------------------------------
extern "C" void kernel_launch(void* const* d_in, const int* in_sizes, int n_in,
                              void* d_out, int out_size, void* d_ws, size_t ws_size,
                              hipStream_t stream) {
    const float* x   = (const float*)d_in[0];
    const int*   ei  = (const int*)d_in[1];     // [2, E] int32; row1 = src
    const float* Wc  = (const float*)d_in[2];   // [96, 192] interleaved
    const float* bc  = (const float*)d_in[3];   // [96]
    float* out = (float*)d_out;

    const int* src = ei + E_;

    float* feats = (float*)d_ws;                         // [BN, 96]
    float* agg   = feats + (size_t)BN_ * C_;             // [BN, 96]

    dim3 gA(N_ / 64, C_ / 32, B_);
    transpose_k<<<gA, 256, 0, stream>>>(x, feats);

    gather_max_k<<<BN_ / 64, 256, 0, stream>>>(feats, src, agg);

    conv_k<<<BN_ / 64, 256, 0, stream>>>(x, agg, Wc, bc, out);
}

// Round 3
// 86.546 us; speedup vs baseline: 2.8465x; 2.8465x over previous
//
#include <hip/hip_runtime.h>

#define B_   16
#define C_   96
#define N_   4096
#define BN_  65536
#define K_   16
#define E_   (BN_ * K_)

typedef __attribute__((ext_vector_type(8))) short bf16x8;
typedef __attribute__((ext_vector_type(4))) float f32x4;

union FragU { uint32_t u[4]; bf16x8 v; };

__device__ __forceinline__ uint32_t pack2_bf16(float a, float b) {
    uint32_t ua = __builtin_bit_cast(uint32_t, a);
    uint32_t ub = __builtin_bit_cast(uint32_t, b);
    ua = (ua + 0x7fffu + ((ua >> 16) & 1u)) >> 16;   // RNE
    ub = (ub + 0x7fffu + ((ub >> 16) & 1u)) >> 16;
    return (ua & 0xffffu) | (ub << 16);
}

// ---------------------------------------------------------------------------
// Kernel A: transpose x [B, C, N] -> feats [BN, C] fp32 (node-major rows)
// ---------------------------------------------------------------------------
__global__ __launch_bounds__(256) void transpose_k(const float* __restrict__ x,
                                                   float* __restrict__ feats) {
    __shared__ float tile[32][65];
    int b  = blockIdx.z;
    int c0 = blockIdx.y * 32;
    int n0 = blockIdx.x * 64;
    const float* xp = x + (size_t)b * C_ * N_;
    for (int t = threadIdx.x; t < 32 * 64; t += 256) {
        int c = t >> 6, n = t & 63;
        tile[c][n] = xp[(size_t)(c0 + c) * N_ + n0 + n];
    }
    __syncthreads();
    float* fp = feats + ((size_t)b * N_ + n0) * C_ + c0;
    for (int t = threadIdx.x; t < 32 * 64; t += 256) {
        int n = t >> 5, c = t & 31;
        fp[(size_t)n * C_ + c] = tile[c][n];
    }
}

// ---------------------------------------------------------------------------
// Kernel B: per-node max over 16 gathered rows, minus own row -> agg bf16
// agg_bf layout: [BN][96] ushort (node-major).
// ---------------------------------------------------------------------------
__global__ __launch_bounds__(256) void gather_max_k(const float* __restrict__ feats,
                                                    const int* __restrict__ src,
                                                    ushort* __restrict__ agg_bf) {
    int tid = threadIdx.x;
    int ln  = tid >> 2;          // local node 0..63
    int r   = tid & 3;           // chunk group 0..3
    size_t i = (size_t)blockIdx.x * 64 + ln;
    const int* s = src + i * K_;

    float4 m[6];
#pragma unroll
    for (int j = 0; j < 6; j++)
        m[j] = make_float4(-3.0e38f, -3.0e38f, -3.0e38f, -3.0e38f);

#pragma unroll
    for (int q = 0; q < 4; q++) {
        int4 iv = ((const int4*)s)[q];
        int ids[4] = {iv.x, iv.y, iv.z, iv.w};
#pragma unroll
        for (int kk = 0; kk < 4; kk++) {
            const float4* sr = (const float4*)(feats + (size_t)ids[kk] * C_);
#pragma unroll
            for (int j = 0; j < 6; j++) {
                float4 v = sr[r + 4 * j];
                m[j].x = fmaxf(m[j].x, v.x);
                m[j].y = fmaxf(m[j].y, v.y);
                m[j].z = fmaxf(m[j].z, v.z);
                m[j].w = fmaxf(m[j].w, v.w);
            }
        }
    }

    const float4* fr = (const float4*)(feats + i * C_);
    ushort* ap = agg_bf + i * (size_t)C_;
#pragma unroll
    for (int j = 0; j < 6; j++) {
        float4 own = fr[r + 4 * j];
        uint2 p;
        p.x = pack2_bf16(m[j].x - own.x, m[j].y - own.y);
        p.y = pack2_bf16(m[j].z - own.z, m[j].w - own.w);
        *(uint2*)(ap + (size_t)(r + 4 * j) * 4) = p;
    }
}

// ---------------------------------------------------------------------------
// Kernel W: pack Wc [96][192] (interleaved x/agg cols) into B-fragment order.
// k-space: k<96 -> x weight (korig=2k), k>=96 -> agg weight (korig=2(k-96)+1).
// Fragment (ks, to): lane l holds col o=to*16+(l&15), elems e:
//   k = ks*32 + 4*(l>>4) + (e&3) + 16*(e>>2)
// Stored as Wp[((ks*6+to)*64 + l)*8 + e] bf16 -> one uint4 per lane.
// ---------------------------------------------------------------------------
__global__ __launch_bounds__(256) void pack_w_k(const float* __restrict__ Wc,
                                                ushort* __restrict__ Wp) {
    int t = blockIdx.x * 256 + threadIdx.x;
    if (t >= 36 * 64) return;
    int fid = t >> 6, l = t & 63;
    int ks = fid / 6, to = fid % 6;
    int o = to * 16 + (l & 15), g = l >> 4;
    uint32_t packed[4];
#pragma unroll
    for (int h = 0; h < 4; h++) {
        int e0 = 2 * h, e1 = 2 * h + 1;
        int k0 = ks * 32 + 4 * g + (e0 & 3) + 16 * (e0 >> 2);
        int k1 = ks * 32 + 4 * g + (e1 & 3) + 16 * (e1 >> 2);
        int ko0 = (k0 < 96) ? 2 * k0 : 2 * (k0 - 96) + 1;
        int ko1 = (k1 < 96) ? 2 * k1 : 2 * (k1 - 96) + 1;
        packed[h] = pack2_bf16(Wc[(size_t)o * 192 + ko0], Wc[(size_t)o * 192 + ko1]);
    }
    uint4 u = make_uint4(packed[0], packed[1], packed[2], packed[3]);
    ((uint4*)Wp)[t] = u;
}

// ---------------------------------------------------------------------------
// Kernel C: MFMA GEMM. D[node][o] = relu(bias + cat[node][:] . W[:][o])
// Block: 256 thr (4 waves), tile = 128 nodes x 96 outs, K=192 in 6 steps.
// A-tile in LDS: [128 n][200 ushort], XOR swizzle (k ^ ((n&15)<<2)) ushorts.
// Wave w: nodes [w*32, w*32+32) = 2 M-tiles; all 6 N(out)-tiles.
// ---------------------------------------------------------------------------
__global__ __launch_bounds__(256) void conv_mfma_k(const float* __restrict__ x,
                                                   const ushort* __restrict__ agg_bf,
                                                   const ushort* __restrict__ Wp,
                                                   const float* __restrict__ bc,
                                                   float* __restrict__ out) {
    __shared__ ushort A_lds[128 * 200];   // 51200 B; reused as [96][132] f32 epilogue
    int tid = threadIdx.x;
    int w = tid >> 6, l = tid & 63;
    int blk = blockIdx.x;
    int b = blk >> 5;
    int n0 = (blk & 31) << 7;   // 128-node tile within batch

    float bcr[6];
#pragma unroll
    for (int to = 0; to < 6; to++) bcr[to] = bc[to * 16 + (l & 15)];

    // ---- stage x part: k = 0..95 (c-major global -> node-major LDS, bf16)
    const float* xb = x + (size_t)b * C_ * N_ + n0;
#pragma unroll
    for (int i = 0; i < 6; i++) {
        int q = w * 6 + i;                 // c quad: c = 4q..4q+3
#pragma unroll
        for (int sub = 0; sub < 2; sub++) {
            int n = sub * 64 + l;
            float v0 = xb[(size_t)(4 * q + 0) * N_ + n];
            float v1 = xb[(size_t)(4 * q + 1) * N_ + n];
            float v2 = xb[(size_t)(4 * q + 2) * N_ + n];
            float v3 = xb[(size_t)(4 * q + 3) * N_ + n];
            uint2 p;
            p.x = pack2_bf16(v0, v1);
            p.y = pack2_bf16(v2, v3);
            int idx = n * 200 + ((4 * q) ^ ((n & 15) << 2));
            *(uint2*)&A_lds[idx] = p;
        }
    }
    // ---- stage agg part: k = 96..191 (already bf16, node-major rows)
    const ushort* ab = agg_bf + ((size_t)b * N_ + n0) * C_;
#pragma unroll
    for (int i = 0; i < 12; i++) {
        int tau = i * 256 + tid;
        int n = tau / 24;
        int qa = tau - n * 24;             // c quad within agg part
        uint2 p = *(const uint2*)(ab + (size_t)n * C_ + 4 * qa);
        int kq = 96 + 4 * qa;
        int idx = n * 200 + (kq ^ ((n & 15) << 2));
        *(uint2*)&A_lds[idx] = p;
    }
    __syncthreads();

    f32x4 acc[2][6];
#pragma unroll
    for (int tm = 0; tm < 2; tm++)
#pragma unroll
        for (int to = 0; to < 6; to++)
            acc[tm][to] = (f32x4){0.f, 0.f, 0.f, 0.f};

    const uint4* wp4 = (const uint4*)Wp;
    int g = l >> 4;
    int m = (l & 15) << 2;                 // swizzle mask (ushort units)

#pragma unroll
    for (int ks = 0; ks < 6; ks++) {
        FragU bfrag[6];
#pragma unroll
        for (int to = 0; to < 6; to++) {
            uint4 u = wp4[(ks * 6 + to) * 64 + l];
            bfrag[to].u[0] = u.x; bfrag[to].u[1] = u.y;
            bfrag[to].u[2] = u.z; bfrag[to].u[3] = u.w;
        }
        FragU afrag[2];
#pragma unroll
        for (int tm = 0; tm < 2; tm++) {
            int n = w * 32 + tm * 16 + (l & 15);
            int base = n * 200;
            int k1 = ks * 32 + 4 * g;
            uint2 lo = *(const uint2*)&A_lds[base + (k1 ^ m)];
            uint2 hi = *(const uint2*)&A_lds[base + ((k1 + 16) ^ m)];
            afrag[tm].u[0] = lo.x; afrag[tm].u[1] = lo.y;
            afrag[tm].u[2] = hi.x; afrag[tm].u[3] = hi.y;
        }
#pragma unroll
        for (int tm = 0; tm < 2; tm++)
#pragma unroll
            for (int to = 0; to < 6; to++)
                acc[tm][to] = __builtin_amdgcn_mfma_f32_16x16x32_bf16(
                    afrag[tm].v, bfrag[to].v, acc[tm][to], 0, 0, 0);
    }

    __syncthreads();
    float* OT = (float*)A_lds;             // [96][132]
#pragma unroll
    for (int tm = 0; tm < 2; tm++)
#pragma unroll
        for (int to = 0; to < 6; to++) {
            int o = to * 16 + (l & 15);
#pragma unroll
            for (int reg = 0; reg < 4; reg++) {
                int nl = w * 32 + tm * 16 + ((l >> 4) << 2) + reg;
                OT[o * 132 + nl] = fmaxf(acc[tm][to][reg] + bcr[to], 0.0f);
            }
        }
    __syncthreads();

#pragma unroll
    for (int i = 0; i < 12; i++) {
        int f = i * 256 + tid;
        int o = f >> 5, c4 = f & 31;
        float4 v = *(const float4*)&OT[o * 132 + 4 * c4];
        *(float4*)(out + ((size_t)b * C_ + o) * N_ + n0 + 4 * c4) = v;
    }
}

// ---------------------------------------------------------------------------
extern "C" void kernel_launch(void* const* d_in, const int* in_sizes, int n_in,
                              void* d_out, int out_size, void* d_ws, size_t ws_size,
                              hipStream_t stream) {
    const float* x   = (const float*)d_in[0];
    const int*   ei  = (const int*)d_in[1];     // [2, E] int32; row1 = src
    const float* Wc  = (const float*)d_in[2];   // [96, 192] interleaved
    const float* bc  = (const float*)d_in[3];   // [96]
    float* out = (float*)d_out;

    const int* src = ei + E_;

    // ws layout: feats fp32 [BN*96] | agg bf16 [BN*96] | Wp bf16 [36*64*8]
    float*  feats  = (float*)d_ws;
    ushort* agg_bf = (ushort*)((char*)d_ws + (size_t)BN_ * C_ * 4);
    ushort* Wp     = (ushort*)((char*)d_ws + (size_t)BN_ * C_ * 4 + (size_t)BN_ * C_ * 2);

    pack_w_k<<<9, 256, 0, stream>>>(Wc, Wp);

    dim3 gA(N_ / 64, C_ / 32, B_);
    transpose_k<<<gA, 256, 0, stream>>>(x, feats);

    gather_max_k<<<BN_ / 64, 256, 0, stream>>>(feats, src, agg_bf);

    conv_mfma_k<<<B_ * (N_ / 128), 256, 0, stream>>>(x, agg_bf, Wp, bc, out);
}

// Round 4
// 59.197 us; speedup vs baseline: 4.1616x; 1.4620x over previous
//
#include <hip/hip_runtime.h>

#define B_   16
#define C_   96
#define N_   4096
#define BN_  65536
#define K_   16
#define E_   (BN_ * K_)

typedef __attribute__((ext_vector_type(8))) short bf16x8;
typedef __attribute__((ext_vector_type(4))) float f32x4;

union FragU { uint32_t u[4]; bf16x8 v; };

__device__ __forceinline__ uint32_t pack2_bf16(float a, float b) {
    uint32_t ua = __builtin_bit_cast(uint32_t, a);
    uint32_t ub = __builtin_bit_cast(uint32_t, b);
    ua = (ua + 0x7fffu + ((ua >> 16) & 1u)) >> 16;   // RNE
    ub = (ub + 0x7fffu + ((ub >> 16) & 1u)) >> 16;
    return (ua & 0xffffu) | (ub << 16);
}
__device__ __forceinline__ float lo16f(uint32_t u) {
    return __builtin_bit_cast(float, u << 16);
}
__device__ __forceinline__ float hi16f(uint32_t u) {
    return __builtin_bit_cast(float, u & 0xffff0000u);
}

// ---------------------------------------------------------------------------
// Kernel A: transpose x [B, C, N] fp32 -> feats_bf [BN, 96] bf16 (node-major)
// ---------------------------------------------------------------------------
__global__ __launch_bounds__(256) void transpose_k(const float* __restrict__ x,
                                                   ushort* __restrict__ feats_bf) {
    __shared__ float tile[32][65];
    int b  = blockIdx.z;
    int c0 = blockIdx.y * 32;
    int n0 = blockIdx.x * 64;
    const float* xp = x + (size_t)b * C_ * N_;
    for (int t = threadIdx.x; t < 32 * 64; t += 256) {
        int c = t >> 6, n = t & 63;
        tile[c][n] = xp[(size_t)(c0 + c) * N_ + n0 + n];
    }
    __syncthreads();
    ushort* fp = feats_bf + ((size_t)b * N_ + n0) * C_ + c0;
    for (int t = threadIdx.x; t < 64 * 16; t += 256) {
        int n = t >> 4, cq = t & 15;
        uint32_t p = pack2_bf16(tile[2 * cq][n], tile[2 * cq + 1][n]);
        *(uint32_t*)(fp + (size_t)n * C_ + 2 * cq) = p;
    }
}

// ---------------------------------------------------------------------------
// Kernel B: per-node max over 16 gathered bf16 rows, minus own row -> agg bf16
// 8 lanes/node, 32 nodes per 256-thread block (2048 blocks -> full occupancy).
// Each lane owns 12 channels as 3 interleaved uint2 chunks (r, r+8, r+16).
// ---------------------------------------------------------------------------
__global__ __launch_bounds__(256) void gather_max_k(const ushort* __restrict__ feats,
                                                    const int* __restrict__ src,
                                                    ushort* __restrict__ agg_bf) {
    int tid = threadIdx.x;
    int ln  = tid >> 3;          // local node 0..31
    int r   = tid & 7;           // chunk lane 0..7
    size_t i = (size_t)blockIdx.x * 32 + ln;
    const int* s = src + i * K_;

    float m[12];
#pragma unroll
    for (int j = 0; j < 12; j++) m[j] = -3.0e38f;

#pragma unroll
    for (int q = 0; q < 4; q++) {
        int4 iv = ((const int4*)s)[q];
        int ids[4] = {iv.x, iv.y, iv.z, iv.w};
#pragma unroll
        for (int kk = 0; kk < 4; kk++) {   // static indexing (no scratch)
            const uint2* row = (const uint2*)(feats + (size_t)ids[kk] * C_);
#pragma unroll
            for (int j = 0; j < 3; j++) {
                uint2 v = row[r + 8 * j];
                m[4 * j + 0] = fmaxf(m[4 * j + 0], lo16f(v.x));
                m[4 * j + 1] = fmaxf(m[4 * j + 1], hi16f(v.x));
                m[4 * j + 2] = fmaxf(m[4 * j + 2], lo16f(v.y));
                m[4 * j + 3] = fmaxf(m[4 * j + 3], hi16f(v.y));
            }
        }
    }

    const uint2* own = (const uint2*)(feats + i * (size_t)C_);
    ushort* ap = agg_bf + i * (size_t)C_;
#pragma unroll
    for (int j = 0; j < 3; j++) {
        uint2 o = own[r + 8 * j];
        uint2 p;
        p.x = pack2_bf16(m[4 * j + 0] - lo16f(o.x), m[4 * j + 1] - hi16f(o.x));
        p.y = pack2_bf16(m[4 * j + 2] - lo16f(o.y), m[4 * j + 3] - hi16f(o.y));
        *(uint2*)(ap + (size_t)(r + 8 * j) * 4) = p;
    }
}

// ---------------------------------------------------------------------------
// Kernel W: pack Wc [96][192] (interleaved x/agg cols) into B-fragment order.
// k-space: k<96 -> x weight (korig=2k), k>=96 -> agg weight (korig=2(k-96)+1).
// Fragment (ks, to): lane l holds col o=to*16+(l&15), elems e:
//   k = ks*32 + 4*(l>>4) + (e&3) + 16*(e>>2)
// ---------------------------------------------------------------------------
__global__ __launch_bounds__(256) void pack_w_k(const float* __restrict__ Wc,
                                                ushort* __restrict__ Wp) {
    int t = blockIdx.x * 256 + threadIdx.x;
    if (t >= 36 * 64) return;
    int fid = t >> 6, l = t & 63;
    int ks = fid / 6, to = fid % 6;
    int o = to * 16 + (l & 15), g = l >> 4;
    uint32_t packed[4];
#pragma unroll
    for (int h = 0; h < 4; h++) {
        int e0 = 2 * h, e1 = 2 * h + 1;
        int k0 = ks * 32 + 4 * g + (e0 & 3) + 16 * (e0 >> 2);
        int k1 = ks * 32 + 4 * g + (e1 & 3) + 16 * (e1 >> 2);
        int ko0 = (k0 < 96) ? 2 * k0 : 2 * (k0 - 96) + 1;
        int ko1 = (k1 < 96) ? 2 * k1 : 2 * (k1 - 96) + 1;
        packed[h] = pack2_bf16(Wc[(size_t)o * 192 + ko0], Wc[(size_t)o * 192 + ko1]);
    }
    uint4 u = make_uint4(packed[0], packed[1], packed[2], packed[3]);
    ((uint4*)Wp)[t] = u;
}

// ---------------------------------------------------------------------------
// Kernel C: MFMA GEMM. D[node][o] = relu(bias + cat[node][:] . W[:][o])
// Block: 256 thr (4 waves), tile = 128 nodes x 96 outs, K=192 in 6 steps.
// A-tile in LDS: [128 n][200 ushort], XOR swizzle (k ^ ((n&15)<<2)) ushorts.
// Both A-halves (x bf16 rows, agg bf16 rows) are node-major contiguous reads.
// ---------------------------------------------------------------------------
__global__ __launch_bounds__(256) void conv_mfma_k(const ushort* __restrict__ feats_bf,
                                                   const ushort* __restrict__ agg_bf,
                                                   const ushort* __restrict__ Wp,
                                                   const float* __restrict__ bc,
                                                   float* __restrict__ out) {
    __shared__ ushort A_lds[128 * 200];   // 51200 B; reused as [96][132] f32 epilogue
    int tid = threadIdx.x;
    int w = tid >> 6, l = tid & 63;
    int blk = blockIdx.x;
    int b = blk >> 5;
    int n0 = (blk & 31) << 7;   // 128-node tile within batch

    float bcr[6];
#pragma unroll
    for (int to = 0; to < 6; to++) bcr[to] = bc[to * 16 + (l & 15)];

    // ---- stage x part: k = 0..95 (node-major bf16 rows, contiguous)
    const ushort* fb = feats_bf + ((size_t)b * N_ + n0) * C_;
#pragma unroll
    for (int i = 0; i < 12; i++) {
        int tau = i * 256 + tid;
        int n = tau / 24;
        int q = tau - n * 24;              // uint2 chunk within row (4 ushorts)
        uint2 p = *(const uint2*)(fb + (size_t)n * C_ + 4 * q);
        int idx = n * 200 + ((4 * q) ^ ((n & 15) << 2));
        *(uint2*)&A_lds[idx] = p;
    }
    // ---- stage agg part: k = 96..191
    const ushort* ab = agg_bf + ((size_t)b * N_ + n0) * C_;
#pragma unroll
    for (int i = 0; i < 12; i++) {
        int tau = i * 256 + tid;
        int n = tau / 24;
        int q = tau - n * 24;
        uint2 p = *(const uint2*)(ab + (size_t)n * C_ + 4 * q);
        int idx = n * 200 + ((96 + 4 * q) ^ ((n & 15) << 2));
        *(uint2*)&A_lds[idx] = p;
    }
    __syncthreads();

    f32x4 acc[2][6];
#pragma unroll
    for (int tm = 0; tm < 2; tm++)
#pragma unroll
        for (int to = 0; to < 6; to++)
            acc[tm][to] = (f32x4){0.f, 0.f, 0.f, 0.f};

    const uint4* wp4 = (const uint4*)Wp;
    int g = l >> 4;
    int m = (l & 15) << 2;                 // swizzle mask (ushort units)

#pragma unroll
    for (int ks = 0; ks < 6; ks++) {
        FragU bfrag[6];
#pragma unroll
        for (int to = 0; to < 6; to++) {
            uint4 u = wp4[(ks * 6 + to) * 64 + l];
            bfrag[to].u[0] = u.x; bfrag[to].u[1] = u.y;
            bfrag[to].u[2] = u.z; bfrag[to].u[3] = u.w;
        }
        FragU afrag[2];
#pragma unroll
        for (int tm = 0; tm < 2; tm++) {
            int n = w * 32 + tm * 16 + (l & 15);
            int base = n * 200;
            int k1 = ks * 32 + 4 * g;
            uint2 lo = *(const uint2*)&A_lds[base + (k1 ^ m)];
            uint2 hi = *(const uint2*)&A_lds[base + ((k1 + 16) ^ m)];
            afrag[tm].u[0] = lo.x; afrag[tm].u[1] = lo.y;
            afrag[tm].u[2] = hi.x; afrag[tm].u[3] = hi.y;
        }
#pragma unroll
        for (int tm = 0; tm < 2; tm++)
#pragma unroll
            for (int to = 0; to < 6; to++)
                acc[tm][to] = __builtin_amdgcn_mfma_f32_16x16x32_bf16(
                    afrag[tm].v, bfrag[to].v, acc[tm][to], 0, 0, 0);
    }

    __syncthreads();
    float* OT = (float*)A_lds;             // [96][132]
#pragma unroll
    for (int tm = 0; tm < 2; tm++)
#pragma unroll
        for (int to = 0; to < 6; to++) {
            int o = to * 16 + (l & 15);
#pragma unroll
            for (int reg = 0; reg < 4; reg++) {
                int nl = w * 32 + tm * 16 + ((l >> 4) << 2) + reg;
                OT[o * 132 + nl] = fmaxf(acc[tm][to][reg] + bcr[to], 0.0f);
            }
        }
    __syncthreads();

#pragma unroll
    for (int i = 0; i < 12; i++) {
        int f = i * 256 + tid;
        int o = f >> 5, c4 = f & 31;
        float4 v = *(const float4*)&OT[o * 132 + 4 * c4];
        *(float4*)(out + ((size_t)b * C_ + o) * N_ + n0 + 4 * c4) = v;
    }
}

// ---------------------------------------------------------------------------
extern "C" void kernel_launch(void* const* d_in, const int* in_sizes, int n_in,
                              void* d_out, int out_size, void* d_ws, size_t ws_size,
                              hipStream_t stream) {
    const float* x   = (const float*)d_in[0];
    const int*   ei  = (const int*)d_in[1];     // [2, E] int32; row1 = src
    const float* Wc  = (const float*)d_in[2];   // [96, 192] interleaved
    const float* bc  = (const float*)d_in[3];   // [96]
    float* out = (float*)d_out;

    const int* src = ei + E_;

    // ws layout: feats bf16 [BN*96] | agg bf16 [BN*96] | Wp bf16 [36*64*8]
    ushort* feats_bf = (ushort*)d_ws;
    ushort* agg_bf   = (ushort*)((char*)d_ws + (size_t)BN_ * C_ * 2);
    ushort* Wp       = (ushort*)((char*)d_ws + (size_t)BN_ * C_ * 4);

    pack_w_k<<<9, 256, 0, stream>>>(Wc, Wp);

    dim3 gA(N_ / 64, C_ / 32, B_);
    transpose_k<<<gA, 256, 0, stream>>>(x, feats_bf);

    gather_max_k<<<BN_ / 32, 256, 0, stream>>>(feats_bf, src, agg_bf);

    conv_mfma_k<<<B_ * (N_ / 128), 256, 0, stream>>>(feats_bf, agg_bf, Wp, bc, out);
}

// Round 5
// 57.010 us; speedup vs baseline: 4.3212x; 1.0384x over previous
//
#include <hip/hip_runtime.h>

#define B_   16
#define C_   96
#define N_   4096
#define BN_  65536
#define K_   16
#define E_   (BN_ * K_)

typedef __attribute__((ext_vector_type(8))) short bf16x8;
typedef __attribute__((ext_vector_type(4))) float f32x4;

union FragU { uint32_t u[4]; bf16x8 v; };

__device__ __forceinline__ uint32_t pack2_bf16(float a, float b) {
    uint32_t ua = __builtin_bit_cast(uint32_t, a);
    uint32_t ub = __builtin_bit_cast(uint32_t, b);
    ua = (ua + 0x7fffu + ((ua >> 16) & 1u)) >> 16;   // RNE
    ub = (ub + 0x7fffu + ((ub >> 16) & 1u)) >> 16;
    return (ua & 0xffffu) | (ub << 16);
}
__device__ __forceinline__ float lo16f(uint32_t u) {
    return __builtin_bit_cast(float, u << 16);
}
__device__ __forceinline__ float hi16f(uint32_t u) {
    return __builtin_bit_cast(float, u & 0xffff0000u);
}

// ---------------------------------------------------------------------------
// Kernel A: transpose x [B, C, N] fp32 -> feats_bf [BN, 96] bf16 (node-major)
// ---------------------------------------------------------------------------
__global__ __launch_bounds__(256) void transpose_k(const float* __restrict__ x,
                                                   ushort* __restrict__ feats_bf) {
    __shared__ float tile[32][65];
    int b  = blockIdx.z;
    int c0 = blockIdx.y * 32;
    int n0 = blockIdx.x * 64;
    const float* xp = x + (size_t)b * C_ * N_;
    for (int t = threadIdx.x; t < 32 * 64; t += 256) {
        int c = t >> 6, n = t & 63;
        tile[c][n] = xp[(size_t)(c0 + c) * N_ + n0 + n];
    }
    __syncthreads();
    ushort* fp = feats_bf + ((size_t)b * N_ + n0) * C_ + c0;
    for (int t = threadIdx.x; t < 64 * 16; t += 256) {
        int n = t >> 4, cq = t & 15;
        uint32_t p = pack2_bf16(tile[2 * cq][n], tile[2 * cq + 1][n]);
        *(uint32_t*)(fp + (size_t)n * C_ + 2 * cq) = p;
    }
}

// ---------------------------------------------------------------------------
// Kernel B: blocks [0,2048): per-node max over 16 gathered bf16 rows, minus
// own row -> agg bf16. 8 lanes/node, 32 nodes per 256-thread block.
// Blocks [2048,2057): pack Wc into MFMA B-fragment order (fused to save a
// dispatch; must complete before conv, which it does trivially).
//   k<96 -> x weight (korig=2k), k>=96 -> agg weight (korig=2(k-96)+1)
//   frag (ks,to): lane l holds col o=to*16+(l&15), elem e at
//   k = ks*32 + 4*(l>>4) + (e&3) + 16*(e>>2)
// ---------------------------------------------------------------------------
__global__ __launch_bounds__(256) void gather_max_k(const ushort* __restrict__ feats,
                                                    const int* __restrict__ src,
                                                    ushort* __restrict__ agg_bf,
                                                    const float* __restrict__ Wc,
                                                    ushort* __restrict__ Wp) {
    int tid = threadIdx.x;
    if (blockIdx.x >= 2048) {
        int t = (blockIdx.x - 2048) * 256 + tid;
        if (t >= 36 * 64) return;
        int fid = t >> 6, l = t & 63;
        int ks = fid / 6, to = fid % 6;
        int o = to * 16 + (l & 15), g = l >> 4;
        uint32_t packed[4];
#pragma unroll
        for (int h = 0; h < 4; h++) {
            int e0 = 2 * h, e1 = 2 * h + 1;
            int k0 = ks * 32 + 4 * g + (e0 & 3) + 16 * (e0 >> 2);
            int k1 = ks * 32 + 4 * g + (e1 & 3) + 16 * (e1 >> 2);
            int ko0 = (k0 < 96) ? 2 * k0 : 2 * (k0 - 96) + 1;
            int ko1 = (k1 < 96) ? 2 * k1 : 2 * (k1 - 96) + 1;
            packed[h] = pack2_bf16(Wc[(size_t)o * 192 + ko0],
                                   Wc[(size_t)o * 192 + ko1]);
        }
        ((uint4*)Wp)[t] = make_uint4(packed[0], packed[1], packed[2], packed[3]);
        return;
    }

    int ln  = tid >> 3;          // local node 0..31
    int r   = tid & 7;           // chunk lane 0..7
    size_t i = (size_t)blockIdx.x * 32 + ln;
    const int* s = src + i * K_;

    float m[12];
#pragma unroll
    for (int j = 0; j < 12; j++) m[j] = -3.0e38f;

#pragma unroll
    for (int q = 0; q < 4; q++) {
        int4 iv = ((const int4*)s)[q];
        int ids[4] = {iv.x, iv.y, iv.z, iv.w};
#pragma unroll
        for (int kk = 0; kk < 4; kk++) {   // static indexing (no scratch)
            const uint2* row = (const uint2*)(feats + (size_t)ids[kk] * C_);
#pragma unroll
            for (int j = 0; j < 3; j++) {
                uint2 v = row[r + 8 * j];
                m[4 * j + 0] = fmaxf(m[4 * j + 0], lo16f(v.x));
                m[4 * j + 1] = fmaxf(m[4 * j + 1], hi16f(v.x));
                m[4 * j + 2] = fmaxf(m[4 * j + 2], lo16f(v.y));
                m[4 * j + 3] = fmaxf(m[4 * j + 3], hi16f(v.y));
            }
        }
    }

    const uint2* own = (const uint2*)(feats + i * (size_t)C_);
    ushort* ap = agg_bf + i * (size_t)C_;
#pragma unroll
    for (int j = 0; j < 3; j++) {
        uint2 o = own[r + 8 * j];
        uint2 p;
        p.x = pack2_bf16(m[4 * j + 0] - lo16f(o.x), m[4 * j + 1] - hi16f(o.x));
        p.y = pack2_bf16(m[4 * j + 2] - lo16f(o.y), m[4 * j + 3] - hi16f(o.y));
        *(uint2*)(ap + (size_t)(r + 8 * j) * 4) = p;
    }
}

// ---------------------------------------------------------------------------
// Kernel C: MFMA GEMM. D[node][o] = relu(bias + cat[node][:] . W[:][o])
// 512 thr (8 waves), tile = 128 nodes x 96 outs, K=192 in 6 steps.
// Wave w owns nodes [w*16, w*16+16).
// A-tile LDS [128 n][200 ushort], swizzle: 4-chunk (4q) ^ ((n&15)<<2).
// Staging exploits: the pair of 8B halves {8j, 8j+4} maps to the SAME 16B
// slot (bits 3-5 of the mask move the slot; bit 2 just swaps halves) ->
// one uint4 load + one ds_write_b128 with halves swapped when n is odd.
// Epilogue: direct float4 global stores (4 acc regs = 4 consecutive n).
// ---------------------------------------------------------------------------
__global__ __launch_bounds__(512) void conv_mfma_k(const ushort* __restrict__ feats_bf,
                                                   const ushort* __restrict__ agg_bf,
                                                   const ushort* __restrict__ Wp,
                                                   const float* __restrict__ bc,
                                                   float* __restrict__ out) {
    __shared__ ushort A_lds[128 * 200];   // 51200 B
    int tid = threadIdx.x;
    int w = tid >> 6, l = tid & 63;
    int blk = blockIdx.x;
    int b = blk >> 5;
    int n0 = (blk & 31) << 7;   // 128-node tile within batch

    float bcr[6];
#pragma unroll
    for (int to = 0; to < 6; to++) bcr[to] = bc[to * 16 + (l & 15)];

    // ---- stage: 128 rows x 24 uint4-chunks (12 feats + 12 agg per row)
    const ushort* fb = feats_bf + ((size_t)b * N_ + n0) * C_;
    const ushort* ab = agg_bf + ((size_t)b * N_ + n0) * C_;
#pragma unroll
    for (int i = 0; i < 6; i++) {
        int tau = i * 512 + tid;
        int n = tau / 24;
        int p = tau - n * 24;              // global uint4 chunk 0..23
        const ushort* srcp = (p < 12) ? (fb + (size_t)n * C_ + 8 * p)
                                      : (ab + (size_t)n * C_ + 8 * (p - 12));
        uint4 u = *(const uint4*)srcp;
        if (n & 1) { uint32_t t0 = u.x, t1 = u.y; u.x = u.z; u.y = u.w; u.z = t0; u.w = t1; }
        int slot = p ^ ((n >> 1) & 7);     // 16B slot index 0..23
        *(uint4*)&A_lds[n * 200 + slot * 8] = u;
    }
    __syncthreads();

    f32x4 acc[6];
#pragma unroll
    for (int to = 0; to < 6; to++) acc[to] = (f32x4){0.f, 0.f, 0.f, 0.f};

    const uint4* wp4 = (const uint4*)Wp;
    int g = l >> 4;
    int m = (l & 15) << 2;                 // swizzle mask (ushort units)
    int nrow = w * 16 + (l & 15);
    int abase = nrow * 200;

#pragma unroll
    for (int ks = 0; ks < 6; ks++) {
        FragU bfrag[6];
#pragma unroll
        for (int to = 0; to < 6; to++) {
            uint4 u = wp4[(ks * 6 + to) * 64 + l];
            bfrag[to].u[0] = u.x; bfrag[to].u[1] = u.y;
            bfrag[to].u[2] = u.z; bfrag[to].u[3] = u.w;
        }
        int k1 = ks * 32 + 4 * g;
        uint2 lo = *(const uint2*)&A_lds[abase + (k1 ^ m)];
        uint2 hi = *(const uint2*)&A_lds[abase + ((k1 + 16) ^ m)];
        FragU afrag;
        afrag.u[0] = lo.x; afrag.u[1] = lo.y;
        afrag.u[2] = hi.x; afrag.u[3] = hi.y;
#pragma unroll
        for (int to = 0; to < 6; to++)
            acc[to] = __builtin_amdgcn_mfma_f32_16x16x32_bf16(
                afrag.v, bfrag[to].v, acc[to], 0, 0, 0);
    }

    // ---- epilogue: direct stores. lane: o = to*16+(l&15), n = w*16+(l>>4)*4+reg
    int nl = n0 + w * 16 + ((l >> 4) << 2);
#pragma unroll
    for (int to = 0; to < 6; to++) {
        int o = to * 16 + (l & 15);
        float4 v;
        v.x = fmaxf(acc[to][0] + bcr[to], 0.0f);
        v.y = fmaxf(acc[to][1] + bcr[to], 0.0f);
        v.z = fmaxf(acc[to][2] + bcr[to], 0.0f);
        v.w = fmaxf(acc[to][3] + bcr[to], 0.0f);
        *(float4*)(out + ((size_t)b * C_ + o) * N_ + nl) = v;
    }
}

// ---------------------------------------------------------------------------
extern "C" void kernel_launch(void* const* d_in, const int* in_sizes, int n_in,
                              void* d_out, int out_size, void* d_ws, size_t ws_size,
                              hipStream_t stream) {
    const float* x   = (const float*)d_in[0];
    const int*   ei  = (const int*)d_in[1];     // [2, E] int32; row1 = src
    const float* Wc  = (const float*)d_in[2];   // [96, 192] interleaved
    const float* bc  = (const float*)d_in[3];   // [96]
    float* out = (float*)d_out;

    const int* src = ei + E_;

    // ws layout: feats bf16 [BN*96] | agg bf16 [BN*96] | Wp bf16 [36*64*8]
    ushort* feats_bf = (ushort*)d_ws;
    ushort* agg_bf   = (ushort*)((char*)d_ws + (size_t)BN_ * C_ * 2);
    ushort* Wp       = (ushort*)((char*)d_ws + (size_t)BN_ * C_ * 4);

    dim3 gA(N_ / 64, C_ / 32, B_);
    transpose_k<<<gA, 256, 0, stream>>>(x, feats_bf);

    gather_max_k<<<2057, 256, 0, stream>>>(feats_bf, src, agg_bf, Wc, Wp);

    conv_mfma_k<<<B_ * (N_ / 128), 512, 0, stream>>>(feats_bf, agg_bf, Wp, bc, out);
}

// Round 6
// 53.053 us; speedup vs baseline: 4.6435x; 1.0746x over previous
//
#include <hip/hip_runtime.h>

#define B_   16
#define C_   96
#define N_   4096
#define BN_  65536
#define K_   16
#define E_   (BN_ * K_)

typedef __attribute__((ext_vector_type(8))) short bf16x8;
typedef __attribute__((ext_vector_type(4))) float f32x4;

union FragU { uint32_t u[4]; bf16x8 v; };

__device__ __forceinline__ uint32_t pack2_bf16(float a, float b) {
    uint32_t ua = __builtin_bit_cast(uint32_t, a);
    uint32_t ub = __builtin_bit_cast(uint32_t, b);
    ua = (ua + 0x7fffu + ((ua >> 16) & 1u)) >> 16;   // RNE
    ub = (ub + 0x7fffu + ((ub >> 16) & 1u)) >> 16;
    return (ua & 0xffffu) | (ub << 16);
}
__device__ __forceinline__ float lo16f(uint32_t u) {
    return __builtin_bit_cast(float, u << 16);
}
__device__ __forceinline__ float hi16f(uint32_t u) {
    return __builtin_bit_cast(float, u & 0xffff0000u);
}

// ---------------------------------------------------------------------------
// Kernel A (flattened grid):
//   blocks [0,3072):    transpose x [B,C,N] fp32 -> feats_bf [BN,96] bf16
//   blocks [3072,3081): pack Wc into MFMA B-fragment order
//     k<96 -> x weight (korig=2k), k>=96 -> agg weight (korig=2(k-96)+1)
//     frag (ks,to): lane l holds col o=to*16+(l&15), elem e at
//     k = ks*32 + 4*(l>>4) + (e&3) + 16*(e>>2)
// ---------------------------------------------------------------------------
__global__ __launch_bounds__(256) void transpose_pack_k(const float* __restrict__ x,
                                                        ushort* __restrict__ feats_bf,
                                                        const float* __restrict__ Wc,
                                                        ushort* __restrict__ Wp) {
    int blk = blockIdx.x;
    if (blk >= 3072) {
        int t = (blk - 3072) * 256 + threadIdx.x;
        if (t >= 36 * 64) return;
        int fid = t >> 6, l = t & 63;
        int ks = fid / 6, to = fid % 6;
        int o = to * 16 + (l & 15), g = l >> 4;
        uint32_t packed[4];
#pragma unroll
        for (int h = 0; h < 4; h++) {
            int e0 = 2 * h, e1 = 2 * h + 1;
            int k0 = ks * 32 + 4 * g + (e0 & 3) + 16 * (e0 >> 2);
            int k1 = ks * 32 + 4 * g + (e1 & 3) + 16 * (e1 >> 2);
            int ko0 = (k0 < 96) ? 2 * k0 : 2 * (k0 - 96) + 1;
            int ko1 = (k1 < 96) ? 2 * k1 : 2 * (k1 - 96) + 1;
            packed[h] = pack2_bf16(Wc[(size_t)o * 192 + ko0],
                                   Wc[(size_t)o * 192 + ko1]);
        }
        ((uint4*)Wp)[t] = make_uint4(packed[0], packed[1], packed[2], packed[3]);
        return;
    }
    __shared__ float tile[32][65];
    int b   = blk / 192;
    int rem = blk - b * 192;
    int c0  = (rem >> 6) * 32;
    int n0  = (rem & 63) * 64;
    const float* xp = x + (size_t)b * C_ * N_;
    for (int t = threadIdx.x; t < 32 * 64; t += 256) {
        int c = t >> 6, n = t & 63;
        tile[c][n] = xp[(size_t)(c0 + c) * N_ + n0 + n];
    }
    __syncthreads();
    ushort* fp = feats_bf + ((size_t)b * N_ + n0) * C_ + c0;
    for (int t = threadIdx.x; t < 64 * 16; t += 256) {
        int n = t >> 4, cq = t & 15;
        uint32_t p = pack2_bf16(tile[2 * cq][n], tile[2 * cq + 1][n]);
        *(uint32_t*)(fp + (size_t)n * C_ + 2 * cq) = p;
    }
}

// ---------------------------------------------------------------------------
// Kernel B: fused gather-max + MFMA conv. One block = 128-node tile.
// 512 thr (8 waves). LDS A-tile [128 n][200 ushort], swizzle (k)^((n&15)<<2).
//  Phase 0: stage own feats rows (k=0..95) — 16B chunks, slot = p ^ ((n>>1)&7)
//           with 8B-half swap when n odd (bit2 of mask).
//  Phase 1: gather 16 random neighbor rows/node, max, minus own row, write
//           bf16 uint2 chunks straight into LDS at k=96+4*qa (same XOR).
//           XOR keeps each 8-aligned slot-group closed -> no overlap with
//           phase 0's slots; every ushort written exactly once.
//  Phase 2: one barrier, 6 K-step MFMA, bias+relu, direct float4 stores.
// ---------------------------------------------------------------------------
__global__ __launch_bounds__(512) void gconv_k(const ushort* __restrict__ feats,
                                               const int* __restrict__ src,
                                               const ushort* __restrict__ Wp,
                                               const float* __restrict__ bc,
                                               float* __restrict__ out) {
    __shared__ ushort A_lds[128 * 200];   // 51200 B
    int tid = threadIdx.x;
    int w = tid >> 6, l = tid & 63;
    int blk = blockIdx.x;
    int b = blk >> 5;
    int n0 = (blk & 31) << 7;

    // ---- phase 0: stage feats rows (k = 0..95), 128 rows x 12 uint4 chunks
    const ushort* fb = feats + ((size_t)b * N_ + n0) * C_;
#pragma unroll
    for (int i = 0; i < 3; i++) {
        int tau = i * 512 + tid;           // 0..1535
        int n = tau / 12;
        int p = tau - n * 12;              // uint4 chunk 0..11
        uint4 u = *(const uint4*)(fb + (size_t)n * C_ + 8 * p);
        if (n & 1) { uint32_t t0 = u.x, t1 = u.y; u.x = u.z; u.y = u.w; u.z = t0; u.w = t1; }
        int slot = p ^ ((n >> 1) & 7);
        *(uint4*)&A_lds[n * 200 + slot * 8] = u;
    }

    // ---- phase 1: gather-max for 128 nodes, 8 lanes/node, 2 passes
#pragma unroll
    for (int s = 0; s < 2; s++) {
        int ln = s * 64 + (tid >> 3);      // tile row 0..127
        int r  = tid & 7;                  // chunk lane 0..7
        size_t i = (size_t)b * N_ + n0 + ln;
        const int* sp = src + i * K_;

        float m[12];
#pragma unroll
        for (int j = 0; j < 12; j++) m[j] = -3.0e38f;

#pragma unroll
        for (int q = 0; q < 4; q++) {
            int4 iv = ((const int4*)sp)[q];
            int ids[4] = {iv.x, iv.y, iv.z, iv.w};
#pragma unroll
            for (int kk = 0; kk < 4; kk++) {   // static indexing (no scratch)
                const uint2* row = (const uint2*)(feats + (size_t)ids[kk] * C_);
#pragma unroll
                for (int j = 0; j < 3; j++) {
                    uint2 v = row[r + 8 * j];
                    m[4 * j + 0] = fmaxf(m[4 * j + 0], lo16f(v.x));
                    m[4 * j + 1] = fmaxf(m[4 * j + 1], hi16f(v.x));
                    m[4 * j + 2] = fmaxf(m[4 * j + 2], lo16f(v.y));
                    m[4 * j + 3] = fmaxf(m[4 * j + 3], hi16f(v.y));
                }
            }
        }

        const uint2* own = (const uint2*)(feats + i * (size_t)C_);
#pragma unroll
        for (int j = 0; j < 3; j++) {
            uint2 o = own[r + 8 * j];
            uint2 p;
            p.x = pack2_bf16(m[4 * j + 0] - lo16f(o.x), m[4 * j + 1] - hi16f(o.x));
            p.y = pack2_bf16(m[4 * j + 2] - lo16f(o.y), m[4 * j + 3] - hi16f(o.y));
            int qa = r + 8 * j;            // agg uint2 chunk 0..23
            int idx = ln * 200 + ((96 + 4 * qa) ^ ((ln & 15) << 2));
            *(uint2*)&A_lds[idx] = p;
        }
    }
    __syncthreads();

    // ---- phase 2: MFMA
    float bcr[6];
#pragma unroll
    for (int to = 0; to < 6; to++) bcr[to] = bc[to * 16 + (l & 15)];

    f32x4 acc[6];
#pragma unroll
    for (int to = 0; to < 6; to++) acc[to] = (f32x4){0.f, 0.f, 0.f, 0.f};

    const uint4* wp4 = (const uint4*)Wp;
    int g = l >> 4;
    int msk = (l & 15) << 2;
    int abase = (w * 16 + (l & 15)) * 200;

#pragma unroll
    for (int ks = 0; ks < 6; ks++) {
        FragU bfrag[6];
#pragma unroll
        for (int to = 0; to < 6; to++) {
            uint4 u = wp4[(ks * 6 + to) * 64 + l];
            bfrag[to].u[0] = u.x; bfrag[to].u[1] = u.y;
            bfrag[to].u[2] = u.z; bfrag[to].u[3] = u.w;
        }
        int k1 = ks * 32 + 4 * g;
        uint2 lo = *(const uint2*)&A_lds[abase + (k1 ^ msk)];
        uint2 hi = *(const uint2*)&A_lds[abase + ((k1 + 16) ^ msk)];
        FragU afrag;
        afrag.u[0] = lo.x; afrag.u[1] = lo.y;
        afrag.u[2] = hi.x; afrag.u[3] = hi.y;
#pragma unroll
        for (int to = 0; to < 6; to++)
            acc[to] = __builtin_amdgcn_mfma_f32_16x16x32_bf16(
                afrag.v, bfrag[to].v, acc[to], 0, 0, 0);
    }

    // ---- epilogue: o = to*16+(l&15), n = n0 + w*16 + (l>>4)*4 + reg
    int nl = n0 + w * 16 + ((l >> 4) << 2);
#pragma unroll
    for (int to = 0; to < 6; to++) {
        int o = to * 16 + (l & 15);
        float4 v;
        v.x = fmaxf(acc[to][0] + bcr[to], 0.0f);
        v.y = fmaxf(acc[to][1] + bcr[to], 0.0f);
        v.z = fmaxf(acc[to][2] + bcr[to], 0.0f);
        v.w = fmaxf(acc[to][3] + bcr[to], 0.0f);
        *(float4*)(out + ((size_t)b * C_ + o) * N_ + nl) = v;
    }
}

// ---------------------------------------------------------------------------
extern "C" void kernel_launch(void* const* d_in, const int* in_sizes, int n_in,
                              void* d_out, int out_size, void* d_ws, size_t ws_size,
                              hipStream_t stream) {
    const float* x   = (const float*)d_in[0];
    const int*   ei  = (const int*)d_in[1];     // [2, E] int32; row1 = src
    const float* Wc  = (const float*)d_in[2];   // [96, 192] interleaved
    const float* bc  = (const float*)d_in[3];   // [96]
    float* out = (float*)d_out;

    const int* src = ei + E_;

    // ws layout: feats bf16 [BN*96] | Wp bf16 [36*64*8]
    ushort* feats_bf = (ushort*)d_ws;
    ushort* Wp       = (ushort*)((char*)d_ws + (size_t)BN_ * C_ * 2);

    transpose_pack_k<<<3081, 256, 0, stream>>>(x, feats_bf, Wc, Wp);

    gconv_k<<<B_ * (N_ / 128), 512, 0, stream>>>(feats_bf, src, Wp, bc, out);
}

// Round 7
// 50.547 us; speedup vs baseline: 4.8737x; 1.0496x over previous
//
#include <hip/hip_runtime.h>

#define B_   16
#define C_   96
#define N_   4096
#define BN_  65536
#define K_   16
#define E_   (BN_ * K_)

typedef __attribute__((ext_vector_type(8))) short bf16x8;
typedef __attribute__((ext_vector_type(4))) float f32x4;

union FragU { uint32_t u[4]; bf16x8 v; };

__device__ __forceinline__ uint32_t pack2_bf16(float a, float b) {
    uint32_t ua = __builtin_bit_cast(uint32_t, a);
    uint32_t ub = __builtin_bit_cast(uint32_t, b);
    ua = (ua + 0x7fffu + ((ua >> 16) & 1u)) >> 16;   // RNE
    ub = (ub + 0x7fffu + ((ub >> 16) & 1u)) >> 16;
    return (ua & 0xffffu) | (ub << 16);
}
__device__ __forceinline__ float lo16f(uint32_t u) {
    return __builtin_bit_cast(float, u << 16);
}
__device__ __forceinline__ float hi16f(uint32_t u) {
    return __builtin_bit_cast(float, u & 0xffff0000u);
}

// ---------------------------------------------------------------------------
// Kernel A (flattened grid):
//   blocks [0,3072):    transpose x [B,C,N] fp32 -> feats_bf [BN,96] bf16
//   blocks [3072,3081): pack Wc into MFMA B-fragment order
//     k<96 -> x weight (korig=2k), k>=96 -> agg weight (korig=2(k-96)+1)
//     frag (ks,to): lane l holds col o=to*16+(l&15), elem e at
//     k = ks*32 + 4*(l>>4) + (e&3) + 16*(e>>2)
// ---------------------------------------------------------------------------
__global__ __launch_bounds__(256) void transpose_pack_k(const float* __restrict__ x,
                                                        ushort* __restrict__ feats_bf,
                                                        const float* __restrict__ Wc,
                                                        ushort* __restrict__ Wp) {
    int blk = blockIdx.x;
    if (blk >= 3072) {
        int t = (blk - 3072) * 256 + threadIdx.x;
        if (t >= 36 * 64) return;
        int fid = t >> 6, l = t & 63;
        int ks = fid / 6, to = fid % 6;
        int o = to * 16 + (l & 15), g = l >> 4;
        uint32_t packed[4];
#pragma unroll
        for (int h = 0; h < 4; h++) {
            int e0 = 2 * h, e1 = 2 * h + 1;
            int k0 = ks * 32 + 4 * g + (e0 & 3) + 16 * (e0 >> 2);
            int k1 = ks * 32 + 4 * g + (e1 & 3) + 16 * (e1 >> 2);
            int ko0 = (k0 < 96) ? 2 * k0 : 2 * (k0 - 96) + 1;
            int ko1 = (k1 < 96) ? 2 * k1 : 2 * (k1 - 96) + 1;
            packed[h] = pack2_bf16(Wc[(size_t)o * 192 + ko0],
                                   Wc[(size_t)o * 192 + ko1]);
        }
        ((uint4*)Wp)[t] = make_uint4(packed[0], packed[1], packed[2], packed[3]);
        return;
    }
    __shared__ float tile[32][65];
    int b   = blk / 192;
    int rem = blk - b * 192;
    int c0  = (rem >> 6) * 32;
    int n0  = (rem & 63) * 64;
    const float* xp = x + (size_t)b * C_ * N_;
    for (int t = threadIdx.x; t < 32 * 64; t += 256) {
        int c = t >> 6, n = t & 63;
        tile[c][n] = xp[(size_t)(c0 + c) * N_ + n0 + n];
    }
    __syncthreads();
    ushort* fp = feats_bf + ((size_t)b * N_ + n0) * C_ + c0;
    for (int t = threadIdx.x; t < 64 * 16; t += 256) {
        int n = t >> 4, cq = t & 15;
        uint32_t p = pack2_bf16(tile[2 * cq][n], tile[2 * cq + 1][n]);
        *(uint32_t*)(fp + (size_t)n * C_ + 2 * cq) = p;
    }
}

// ---------------------------------------------------------------------------
// Kernel B: fused gather-max + MFMA conv. One block = 64-node tile.
// 512 thr (8 waves), grid BN/64 = 1024 -> 4 blocks/CU, 32 waves/CU.
// LDS A-tile [64 n][200 ushort] = 25600 B, swizzle (k)^((n&15)<<2) (verified).
//  Phase 0: stage own feats rows (k=0..95): 16B slot = p ^ ((n>>1)&7),
//           8B halves swapped when n odd. Barrier.
//  Phase 1: 8 lanes/node (one pass, 512 thr = 64 nodes x 8): gather 16
//           random rows, running max; own row read back FROM LDS (same
//           XOR formula); diff -> bf16 -> LDS agg half (k=96..191). Barrier.
//  Phase 2: wave w: M-tile tm=w>>1 (nodes tm*16..+16), out-half th=w&1
//           (to = th*3+{0,1,2}): 3 accs, 6 K-steps. Bias+relu, direct
//           float4 stores.
// ---------------------------------------------------------------------------
__global__ __launch_bounds__(512) void gconv_k(const ushort* __restrict__ feats,
                                               const int* __restrict__ src,
                                               const ushort* __restrict__ Wp,
                                               const float* __restrict__ bc,
                                               float* __restrict__ out) {
    __shared__ ushort A_lds[64 * 200];    // 25600 B
    int tid = threadIdx.x;
    int blk = blockIdx.x;
    int b = blk >> 6;
    int n0 = (blk & 63) << 6;

    // ---- phase 0: stage feats rows (k = 0..95), 64 rows x 12 uint4 chunks
    const ushort* fb = feats + ((size_t)b * N_ + n0) * C_;
#pragma unroll
    for (int i = 0; i < 2; i++) {
        int tau = i * 512 + tid;           // 0..1023, need 0..767
        if (tau < 768) {
            int n = tau / 12;
            int p = tau - n * 12;          // uint4 chunk 0..11
            uint4 u = *(const uint4*)(fb + (size_t)n * C_ + 8 * p);
            if (n & 1) { uint32_t t0 = u.x, t1 = u.y; u.x = u.z; u.y = u.w; u.z = t0; u.w = t1; }
            int slot = p ^ ((n >> 1) & 7);
            *(uint4*)&A_lds[n * 200 + slot * 8] = u;
        }
    }
    __syncthreads();

    // ---- phase 1: gather-max, 64 nodes x 8 lanes (single pass)
    {
        int ln = tid >> 3;                 // tile row 0..63
        int r  = tid & 7;                  // chunk lane 0..7
        size_t i = (size_t)b * N_ + n0 + ln;
        const int* sp = src + i * K_;

        float m[12];
#pragma unroll
        for (int j = 0; j < 12; j++) m[j] = -3.0e38f;

#pragma unroll
        for (int q = 0; q < 4; q++) {
            int4 iv = ((const int4*)sp)[q];
            int ids[4] = {iv.x, iv.y, iv.z, iv.w};
#pragma unroll
            for (int kk = 0; kk < 4; kk++) {   // static indexing (no scratch)
                const uint2* row = (const uint2*)(feats + (size_t)ids[kk] * C_);
#pragma unroll
                for (int j = 0; j < 3; j++) {
                    uint2 v = row[r + 8 * j];
                    m[4 * j + 0] = fmaxf(m[4 * j + 0], lo16f(v.x));
                    m[4 * j + 1] = fmaxf(m[4 * j + 1], hi16f(v.x));
                    m[4 * j + 2] = fmaxf(m[4 * j + 2], lo16f(v.y));
                    m[4 * j + 3] = fmaxf(m[4 * j + 3], hi16f(v.y));
                }
            }
        }

        // own row from LDS (same swizzle formula as the MFMA read side)
        int omsk = (ln & 15) << 2;
#pragma unroll
        for (int j = 0; j < 3; j++) {
            int qa = r + 8 * j;            // chunk 0..23
            uint2 o = *(const uint2*)&A_lds[ln * 200 + ((4 * qa) ^ omsk)];
            uint2 p;
            p.x = pack2_bf16(m[4 * j + 0] - lo16f(o.x), m[4 * j + 1] - hi16f(o.x));
            p.y = pack2_bf16(m[4 * j + 2] - lo16f(o.y), m[4 * j + 3] - hi16f(o.y));
            *(uint2*)&A_lds[ln * 200 + ((96 + 4 * qa) ^ omsk)] = p;
        }
    }
    __syncthreads();

    // ---- phase 2: MFMA. wave w: tm = w>>1, th = w&1.
    int w = tid >> 6, l = tid & 63;
    int tm = w >> 1, th = w & 1;

    float bcr[3];
#pragma unroll
    for (int j = 0; j < 3; j++) bcr[j] = bc[(th * 3 + j) * 16 + (l & 15)];

    f32x4 acc[3];
#pragma unroll
    for (int j = 0; j < 3; j++) acc[j] = (f32x4){0.f, 0.f, 0.f, 0.f};

    const uint4* wp4 = (const uint4*)Wp;
    int g = l >> 4;
    int msk = (l & 15) << 2;
    int abase = (tm * 16 + (l & 15)) * 200;

#pragma unroll
    for (int ks = 0; ks < 6; ks++) {
        FragU bfrag[3];
#pragma unroll
        for (int j = 0; j < 3; j++) {
            uint4 u = wp4[(ks * 6 + th * 3 + j) * 64 + l];
            bfrag[j].u[0] = u.x; bfrag[j].u[1] = u.y;
            bfrag[j].u[2] = u.z; bfrag[j].u[3] = u.w;
        }
        int k1 = ks * 32 + 4 * g;
        uint2 lo = *(const uint2*)&A_lds[abase + (k1 ^ msk)];
        uint2 hi = *(const uint2*)&A_lds[abase + ((k1 + 16) ^ msk)];
        FragU afrag;
        afrag.u[0] = lo.x; afrag.u[1] = lo.y;
        afrag.u[2] = hi.x; afrag.u[3] = hi.y;
#pragma unroll
        for (int j = 0; j < 3; j++)
            acc[j] = __builtin_amdgcn_mfma_f32_16x16x32_bf16(
                afrag.v, bfrag[j].v, acc[j], 0, 0, 0);
    }

    // ---- epilogue: o = (th*3+j)*16+(l&15), n = n0 + tm*16 + (l>>4)*4 + reg
    int nl = n0 + tm * 16 + ((l >> 4) << 2);
#pragma unroll
    for (int j = 0; j < 3; j++) {
        int o = (th * 3 + j) * 16 + (l & 15);
        float4 v;
        v.x = fmaxf(acc[j][0] + bcr[j], 0.0f);
        v.y = fmaxf(acc[j][1] + bcr[j], 0.0f);
        v.z = fmaxf(acc[j][2] + bcr[j], 0.0f);
        v.w = fmaxf(acc[j][3] + bcr[j], 0.0f);
        *(float4*)(out + ((size_t)b * C_ + o) * N_ + nl) = v;
    }
}

// ---------------------------------------------------------------------------
extern "C" void kernel_launch(void* const* d_in, const int* in_sizes, int n_in,
                              void* d_out, int out_size, void* d_ws, size_t ws_size,
                              hipStream_t stream) {
    const float* x   = (const float*)d_in[0];
    const int*   ei  = (const int*)d_in[1];     // [2, E] int32; row1 = src
    const float* Wc  = (const float*)d_in[2];   // [96, 192] interleaved
    const float* bc  = (const float*)d_in[3];   // [96]
    float* out = (float*)d_out;

    const int* src = ei + E_;

    // ws layout: feats bf16 [BN*96] | Wp bf16 [36*64*8]
    ushort* feats_bf = (ushort*)d_ws;
    ushort* Wp       = (ushort*)((char*)d_ws + (size_t)BN_ * C_ * 2);

    transpose_pack_k<<<3081, 256, 0, stream>>>(x, feats_bf, Wc, Wp);

    gconv_k<<<BN_ / 64, 512, 0, stream>>>(feats_bf, src, Wp, bc, out);
}

// Round 8
// 49.872 us; speedup vs baseline: 4.9397x; 1.0135x over previous
//
#include <hip/hip_runtime.h>

#define B_   16
#define C_   96
#define N_   4096
#define BN_  65536
#define K_   16
#define E_   (BN_ * K_)

typedef __attribute__((ext_vector_type(8))) short bf16x8;
typedef __attribute__((ext_vector_type(4))) float f32x4;

union FragU { uint32_t u[4]; bf16x8 v; };

__device__ __forceinline__ uint32_t pack2_bf16(float a, float b) {
    uint32_t ua = __builtin_bit_cast(uint32_t, a);
    uint32_t ub = __builtin_bit_cast(uint32_t, b);
    ua = (ua + 0x7fffu + ((ua >> 16) & 1u)) >> 16;   // RNE
    ub = (ub + 0x7fffu + ((ub >> 16) & 1u)) >> 16;
    return (ua & 0xffffu) | (ub << 16);
}
__device__ __forceinline__ float lo16f(uint32_t u) {
    return __builtin_bit_cast(float, u << 16);
}
__device__ __forceinline__ float hi16f(uint32_t u) {
    return __builtin_bit_cast(float, u & 0xffff0000u);
}

// ---------------------------------------------------------------------------
// Kernel A (flattened grid):
//   blocks [0,1024):    transpose x [B,C,N] fp32 -> feats_bf [BN,96] bf16.
//     One block = 64 nodes x 96 channels. float4 global loads, LDS tile
//     [96][65] (pad 65: write/read aliasing <=2-way = free), each thread
//     packs 24 channels of one node -> 3 x uint4 stores (full 192 B rows
//     written by 4 consecutive lanes).
//   blocks [1024,1033): pack Wc into MFMA B-fragment order
//     k<96 -> x weight (korig=2k), k>=96 -> agg weight (korig=2(k-96)+1)
//     frag (ks,to): lane l holds col o=to*16+(l&15), elem e at
//     k = ks*32 + 4*(l>>4) + (e&3) + 16*(e>>2)
// ---------------------------------------------------------------------------
__global__ __launch_bounds__(256) void transpose_pack_k(const float* __restrict__ x,
                                                        ushort* __restrict__ feats_bf,
                                                        const float* __restrict__ Wc,
                                                        ushort* __restrict__ Wp) {
    int blk = blockIdx.x;
    if (blk >= 1024) {
        int t = (blk - 1024) * 256 + threadIdx.x;
        if (t >= 36 * 64) return;
        int fid = t >> 6, l = t & 63;
        int ks = fid / 6, to = fid % 6;
        int o = to * 16 + (l & 15), g = l >> 4;
        uint32_t packed[4];
#pragma unroll
        for (int h = 0; h < 4; h++) {
            int e0 = 2 * h, e1 = 2 * h + 1;
            int k0 = ks * 32 + 4 * g + (e0 & 3) + 16 * (e0 >> 2);
            int k1 = ks * 32 + 4 * g + (e1 & 3) + 16 * (e1 >> 2);
            int ko0 = (k0 < 96) ? 2 * k0 : 2 * (k0 - 96) + 1;
            int ko1 = (k1 < 96) ? 2 * k1 : 2 * (k1 - 96) + 1;
            packed[h] = pack2_bf16(Wc[(size_t)o * 192 + ko0],
                                   Wc[(size_t)o * 192 + ko1]);
        }
        ((uint4*)Wp)[t] = make_uint4(packed[0], packed[1], packed[2], packed[3]);
        return;
    }

    __shared__ float tile[96][65];        // 24960 B
    int b  = blk >> 6;
    int n0 = (blk & 63) << 6;
    const float* xp = x + (size_t)b * C_ * N_ + n0;

    // load: 96 c-rows x 16 float4 along n, fully coalesced
#pragma unroll
    for (int i = 0; i < 6; i++) {
        int t = i * 256 + threadIdx.x;    // 0..1535
        int c = t >> 4, q = t & 15;
        float4 v = *(const float4*)(xp + (size_t)c * N_ + 4 * q);
        tile[c][4 * q + 0] = v.x; tile[c][4 * q + 1] = v.y;
        tile[c][4 * q + 2] = v.z; tile[c][4 * q + 3] = v.w;
    }
    __syncthreads();

    // store: node n = tid>>2, channel block r*24; 3 x uint4 per thread
    int n = threadIdx.x >> 2, r = threadIdx.x & 3;
    ushort* fp = feats_bf + ((size_t)b * N_ + n0 + n) * C_ + r * 24;
#pragma unroll
    for (int j = 0; j < 3; j++) {
        int c0 = r * 24 + j * 8;
        uint4 u;
        u.x = pack2_bf16(tile[c0 + 0][n], tile[c0 + 1][n]);
        u.y = pack2_bf16(tile[c0 + 2][n], tile[c0 + 3][n]);
        u.z = pack2_bf16(tile[c0 + 4][n], tile[c0 + 5][n]);
        u.w = pack2_bf16(tile[c0 + 6][n], tile[c0 + 7][n]);
        *(uint4*)(fp + j * 8) = u;
    }
}

// ---------------------------------------------------------------------------
// Kernel B: fused gather-max + MFMA conv. One block = 64-node tile.
// 512 thr (8 waves), grid BN/64 = 1024 -> 4 blocks/CU, 32 waves/CU.
// LDS A-tile [64 n][200 ushort] = 25600 B, swizzle (k)^((n&15)<<2) (verified).
//  Pre:     hoist the 4 int4 neighbor-index loads (issue before staging).
//  Phase 0: stage own feats rows (k=0..95): 16B slot = p ^ ((n>>1)&7),
//           8B halves swapped when n odd. Barrier.
//  Phase 1: 8 lanes/node: gather 16 random rows, running max; own row read
//           back FROM LDS (same XOR formula); diff -> bf16 -> LDS agg half
//           (k=96..191). Barrier.
//  Phase 2: wave w: M-tile tm=w>>1, out-half th=w&1: 3 accs, 6 K-steps.
//           Bias+relu, direct float4 stores.
// ---------------------------------------------------------------------------
__global__ __launch_bounds__(512) void gconv_k(const ushort* __restrict__ feats,
                                               const int* __restrict__ src,
                                               const ushort* __restrict__ Wp,
                                               const float* __restrict__ bc,
                                               float* __restrict__ out) {
    __shared__ ushort A_lds[64 * 200];    // 25600 B
    int tid = threadIdx.x;
    int blk = blockIdx.x;
    int b = blk >> 6;
    int n0 = (blk & 63) << 6;

    // ---- pre: issue neighbor-index loads first (critical path)
    int ln = tid >> 3;                     // tile row 0..63
    int r  = tid & 7;                      // chunk lane 0..7
    size_t inode = (size_t)b * N_ + n0 + ln;
    const int4* sp4 = (const int4*)(src + inode * K_);
    int4 ivs[4];
#pragma unroll
    for (int q = 0; q < 4; q++) ivs[q] = sp4[q];

    // ---- phase 0: stage feats rows (k = 0..95), 64 rows x 12 uint4 chunks
    const ushort* fb = feats + ((size_t)b * N_ + n0) * C_;
#pragma unroll
    for (int i = 0; i < 2; i++) {
        int tau = i * 512 + tid;           // 0..1023, need 0..767
        if (tau < 768) {
            int n = tau / 12;
            int p = tau - n * 12;          // uint4 chunk 0..11
            uint4 u = *(const uint4*)(fb + (size_t)n * C_ + 8 * p);
            if (n & 1) { uint32_t t0 = u.x, t1 = u.y; u.x = u.z; u.y = u.w; u.z = t0; u.w = t1; }
            int slot = p ^ ((n >> 1) & 7);
            *(uint4*)&A_lds[n * 200 + slot * 8] = u;
        }
    }
    __syncthreads();

    // ---- phase 1: gather-max, 64 nodes x 8 lanes (single pass)
    {
        float m[12];
#pragma unroll
        for (int j = 0; j < 12; j++) m[j] = -3.0e38f;

#pragma unroll
        for (int q = 0; q < 4; q++) {
            int ids[4] = {ivs[q].x, ivs[q].y, ivs[q].z, ivs[q].w};
#pragma unroll
            for (int kk = 0; kk < 4; kk++) {   // static indexing (no scratch)
                const uint2* row = (const uint2*)(feats + (size_t)ids[kk] * C_);
#pragma unroll
                for (int j = 0; j < 3; j++) {
                    uint2 v = row[r + 8 * j];
                    m[4 * j + 0] = fmaxf(m[4 * j + 0], lo16f(v.x));
                    m[4 * j + 1] = fmaxf(m[4 * j + 1], hi16f(v.x));
                    m[4 * j + 2] = fmaxf(m[4 * j + 2], lo16f(v.y));
                    m[4 * j + 3] = fmaxf(m[4 * j + 3], hi16f(v.y));
                }
            }
        }

        // own row from LDS (same swizzle formula as the MFMA read side)
        int omsk = (ln & 15) << 2;
#pragma unroll
        for (int j = 0; j < 3; j++) {
            int qa = r + 8 * j;            // chunk 0..23
            uint2 o = *(const uint2*)&A_lds[ln * 200 + ((4 * qa) ^ omsk)];
            uint2 p;
            p.x = pack2_bf16(m[4 * j + 0] - lo16f(o.x), m[4 * j + 1] - hi16f(o.x));
            p.y = pack2_bf16(m[4 * j + 2] - lo16f(o.y), m[4 * j + 3] - hi16f(o.y));
            *(uint2*)&A_lds[ln * 200 + ((96 + 4 * qa) ^ omsk)] = p;
        }
    }
    __syncthreads();

    // ---- phase 2: MFMA. wave w: tm = w>>1, th = w&1.
    int w = tid >> 6, l = tid & 63;
    int tm = w >> 1, th = w & 1;

    float bcr[3];
#pragma unroll
    for (int j = 0; j < 3; j++) bcr[j] = bc[(th * 3 + j) * 16 + (l & 15)];

    f32x4 acc[3];
#pragma unroll
    for (int j = 0; j < 3; j++) acc[j] = (f32x4){0.f, 0.f, 0.f, 0.f};

    const uint4* wp4 = (const uint4*)Wp;
    int g = l >> 4;
    int msk = (l & 15) << 2;
    int abase = (tm * 16 + (l & 15)) * 200;

#pragma unroll
    for (int ks = 0; ks < 6; ks++) {
        FragU bfrag[3];
#pragma unroll
        for (int j = 0; j < 3; j++) {
            uint4 u = wp4[(ks * 6 + th * 3 + j) * 64 + l];
            bfrag[j].u[0] = u.x; bfrag[j].u[1] = u.y;
            bfrag[j].u[2] = u.z; bfrag[j].u[3] = u.w;
        }
        int k1 = ks * 32 + 4 * g;
        uint2 lo = *(const uint2*)&A_lds[abase + (k1 ^ msk)];
        uint2 hi = *(const uint2*)&A_lds[abase + ((k1 + 16) ^ msk)];
        FragU afrag;
        afrag.u[0] = lo.x; afrag.u[1] = lo.y;
        afrag.u[2] = hi.x; afrag.u[3] = hi.y;
#pragma unroll
        for (int j = 0; j < 3; j++)
            acc[j] = __builtin_amdgcn_mfma_f32_16x16x32_bf16(
                afrag.v, bfrag[j].v, acc[j], 0, 0, 0);
    }

    // ---- epilogue: o = (th*3+j)*16+(l&15), n = n0 + tm*16 + (l>>4)*4 + reg
    int nl = n0 + tm * 16 + ((l >> 4) << 2);
#pragma unroll
    for (int j = 0; j < 3; j++) {
        int o = (th * 3 + j) * 16 + (l & 15);
        float4 v;
        v.x = fmaxf(acc[j][0] + bcr[j], 0.0f);
        v.y = fmaxf(acc[j][1] + bcr[j], 0.0f);
        v.z = fmaxf(acc[j][2] + bcr[j], 0.0f);
        v.w = fmaxf(acc[j][3] + bcr[j], 0.0f);
        *(float4*)(out + ((size_t)b * C_ + o) * N_ + nl) = v;
    }
}

// ---------------------------------------------------------------------------
extern "C" void kernel_launch(void* const* d_in, const int* in_sizes, int n_in,
                              void* d_out, int out_size, void* d_ws, size_t ws_size,
                              hipStream_t stream) {
    const float* x   = (const float*)d_in[0];
    const int*   ei  = (const int*)d_in[1];     // [2, E] int32; row1 = src
    const float* Wc  = (const float*)d_in[2];   // [96, 192] interleaved
    const float* bc  = (const float*)d_in[3];   // [96]
    float* out = (float*)d_out;

    const int* src = ei + E_;

    // ws layout: feats bf16 [BN*96] | Wp bf16 [36*64*8]
    ushort* feats_bf = (ushort*)d_ws;
    ushort* Wp       = (ushort*)((char*)d_ws + (size_t)BN_ * C_ * 2);

    transpose_pack_k<<<1033, 256, 0, stream>>>(x, feats_bf, Wc, Wp);

    gconv_k<<<BN_ / 64, 512, 0, stream>>>(feats_bf, src, Wp, bc, out);
}

// Round 10
// 49.818 us; speedup vs baseline: 4.9451x; 1.0011x over previous
//
#include <hip/hip_runtime.h>

#define B_   16
#define C_   96
#define N_   4096
#define BN_  65536
#define K_   16
#define E_   (BN_ * K_)

typedef __attribute__((ext_vector_type(8))) short bf16x8;
typedef __attribute__((ext_vector_type(4))) float f32x4;

union FragU { uint32_t u[4]; bf16x8 v; };

__device__ __forceinline__ uint32_t pack2_bf16(float a, float b) {
    uint32_t ua = __builtin_bit_cast(uint32_t, a);
    uint32_t ub = __builtin_bit_cast(uint32_t, b);
    ua = (ua + 0x7fffu + ((ua >> 16) & 1u)) >> 16;   // RNE
    ub = (ub + 0x7fffu + ((ub >> 16) & 1u)) >> 16;
    return (ua & 0xffffu) | (ub << 16);
}
__device__ __forceinline__ float lo16f(uint32_t u) {
    return __builtin_bit_cast(float, u << 16);
}
__device__ __forceinline__ float hi16f(uint32_t u) {
    return __builtin_bit_cast(float, u & 0xffff0000u);
}

// ---------------------------------------------------------------------------
// Kernel A (flattened grid):
//   blocks [0,1024):    transpose x [B,C,N] fp32 -> feats_bf [BN,96] bf16.
//     One block = 64 nodes x 96 channels. float4 global loads, LDS tile
//     [96][65], each thread packs 24 channels of one node -> 3 x uint4.
//   blocks [1024,1033): pack Wc into MFMA B-fragment order
//     k<96 -> x weight (korig=2k), k>=96 -> agg weight (korig=2(k-96)+1)
//     frag (ks,to): lane l holds col o=to*16+(l&15), elem e at
//     k = ks*32 + 4*(l>>4) + (e&3) + 16*(e>>2)
// ---------------------------------------------------------------------------
__global__ __launch_bounds__(256) void transpose_pack_k(const float* __restrict__ x,
                                                        ushort* __restrict__ feats_bf,
                                                        const float* __restrict__ Wc,
                                                        ushort* __restrict__ Wp) {
    int blk = blockIdx.x;
    if (blk >= 1024) {
        int t = (blk - 1024) * 256 + threadIdx.x;
        if (t >= 36 * 64) return;
        int fid = t >> 6, l = t & 63;
        int ks = fid / 6, to = fid % 6;
        int o = to * 16 + (l & 15), g = l >> 4;
        uint32_t packed[4];
#pragma unroll
        for (int h = 0; h < 4; h++) {
            int e0 = 2 * h, e1 = 2 * h + 1;
            int k0 = ks * 32 + 4 * g + (e0 & 3) + 16 * (e0 >> 2);
            int k1 = ks * 32 + 4 * g + (e1 & 3) + 16 * (e1 >> 2);
            int ko0 = (k0 < 96) ? 2 * k0 : 2 * (k0 - 96) + 1;
            int ko1 = (k1 < 96) ? 2 * k1 : 2 * (k1 - 96) + 1;
            packed[h] = pack2_bf16(Wc[(size_t)o * 192 + ko0],
                                   Wc[(size_t)o * 192 + ko1]);
        }
        ((uint4*)Wp)[t] = make_uint4(packed[0], packed[1], packed[2], packed[3]);
        return;
    }

    __shared__ float tile[96][65];        // 24960 B
    int b  = blk >> 6;
    int n0 = (blk & 63) << 6;
    const float* xp = x + (size_t)b * C_ * N_ + n0;

    // load: 96 c-rows x 16 float4 along n, fully coalesced
#pragma unroll
    for (int i = 0; i < 6; i++) {
        int t = i * 256 + threadIdx.x;    // 0..1535
        int c = t >> 4, q = t & 15;
        float4 v = *(const float4*)(xp + (size_t)c * N_ + 4 * q);
        tile[c][4 * q + 0] = v.x; tile[c][4 * q + 1] = v.y;
        tile[c][4 * q + 2] = v.z; tile[c][4 * q + 3] = v.w;
    }
    __syncthreads();

    // store: node n = tid>>2, channel block r*24; 3 x uint4 per thread
    int n = threadIdx.x >> 2, r = threadIdx.x & 3;
    ushort* fp = feats_bf + ((size_t)b * N_ + n0 + n) * C_ + r * 24;
#pragma unroll
    for (int j = 0; j < 3; j++) {
        int c0 = r * 24 + j * 8;
        uint4 u;
        u.x = pack2_bf16(tile[c0 + 0][n], tile[c0 + 1][n]);
        u.y = pack2_bf16(tile[c0 + 2][n], tile[c0 + 3][n]);
        u.z = pack2_bf16(tile[c0 + 4][n], tile[c0 + 5][n]);
        u.w = pack2_bf16(tile[c0 + 6][n], tile[c0 + 7][n]);
        *(uint4*)(fp + j * 8) = u;
    }
}

// ---------------------------------------------------------------------------
// Kernel B: fused gather-max + MFMA conv. One block = 64-node tile.
// 512 thr (8 waves), grid BN/64 = 1024 -> 4 blocks/CU, 32 waves/CU.
// LDS A-tile [64 n][200 ushort] = 25600 B, swizzle (k)^((n&15)<<2) (verified).
//  Pre:     hoist the 4 int4 neighbor-index loads (issue before staging).
//  Phase 0: stage own feats rows (k=0..95): 16B slot = p ^ ((n>>1)&7),
//           8B halves swapped when n odd. Barrier.
//  Phase 1: 8 lanes/node: gather 16 random rows IN PAIRS (both rows' 3
//           uint2 chunks issued before any max -> 2x outstanding loads);
//           own row read back FROM LDS (same XOR formula); diff -> bf16 ->
//           LDS agg half (k=96..191). Barrier.
//  Phase 2: wave w: M-tile tm=w>>1, out-half th=w&1: 3 accs, 6 K-steps.
//           Bias+relu, direct float4 stores.
// ---------------------------------------------------------------------------
__global__ __launch_bounds__(512) void gconv_k(const ushort* __restrict__ feats,
                                               const int* __restrict__ src,
                                               const ushort* __restrict__ Wp,
                                               const float* __restrict__ bc,
                                               float* __restrict__ out) {
    __shared__ ushort A_lds[64 * 200];    // 25600 B
    int tid = threadIdx.x;
    int blk = blockIdx.x;
    int b = blk >> 6;
    int n0 = (blk & 63) << 6;

    // ---- pre: issue neighbor-index loads first (critical path)
    int ln = tid >> 3;                     // tile row 0..63
    int r  = tid & 7;                      // chunk lane 0..7
    size_t inode = (size_t)b * N_ + n0 + ln;
    const int4* sp4 = (const int4*)(src + inode * K_);
    int4 ivs[4];
#pragma unroll
    for (int q = 0; q < 4; q++) ivs[q] = sp4[q];

    // ---- phase 0: stage feats rows (k = 0..95), 64 rows x 12 uint4 chunks
    const ushort* fb = feats + ((size_t)b * N_ + n0) * C_;
    {
        int n = tid / 12, p = tid - n * 12;
        uint4 u = *(const uint4*)(fb + (size_t)n * C_ + 8 * p);
        if (n & 1) { uint32_t t0 = u.x, t1 = u.y; u.x = u.z; u.y = u.w; u.z = t0; u.w = t1; }
        *(uint4*)&A_lds[n * 200 + (p ^ ((n >> 1) & 7)) * 8] = u;
    }
    if (tid < 256) {
        int tau = 512 + tid;
        int n = tau / 12, p = tau - n * 12;
        uint4 u = *(const uint4*)(fb + (size_t)n * C_ + 8 * p);
        if (n & 1) { uint32_t t0 = u.x, t1 = u.y; u.x = u.z; u.y = u.w; u.z = t0; u.w = t1; }
        *(uint4*)&A_lds[n * 200 + (p ^ ((n >> 1) & 7)) * 8] = u;
    }
    __syncthreads();

    // ---- phase 1: gather-max, 64 nodes x 8 lanes, rows processed in pairs
    {
        float m[12];
#pragma unroll
        for (int j = 0; j < 12; j++) m[j] = -3.0e38f;

#pragma unroll
        for (int q = 0; q < 4; q++) {
            int ids[4] = {ivs[q].x, ivs[q].y, ivs[q].z, ivs[q].w};
#pragma unroll
            for (int kk = 0; kk < 4; kk += 2) {   // pair: 6 loads in flight
                const uint2* rowA = (const uint2*)(feats + (size_t)ids[kk] * C_);
                const uint2* rowB = (const uint2*)(feats + (size_t)ids[kk + 1] * C_);
                uint2 va0 = rowA[r];      uint2 vb0 = rowB[r];
                uint2 va1 = rowA[r + 8];  uint2 vb1 = rowB[r + 8];
                uint2 va2 = rowA[r + 16]; uint2 vb2 = rowB[r + 16];
                m[0]  = fmaxf(m[0],  fmaxf(lo16f(va0.x), lo16f(vb0.x)));
                m[1]  = fmaxf(m[1],  fmaxf(hi16f(va0.x), hi16f(vb0.x)));
                m[2]  = fmaxf(m[2],  fmaxf(lo16f(va0.y), lo16f(vb0.y)));
                m[3]  = fmaxf(m[3],  fmaxf(hi16f(va0.y), hi16f(vb0.y)));
                m[4]  = fmaxf(m[4],  fmaxf(lo16f(va1.x), lo16f(vb1.x)));
                m[5]  = fmaxf(m[5],  fmaxf(hi16f(va1.x), hi16f(vb1.x)));
                m[6]  = fmaxf(m[6],  fmaxf(lo16f(va1.y), lo16f(vb1.y)));
                m[7]  = fmaxf(m[7],  fmaxf(hi16f(va1.y), hi16f(vb1.y)));
                m[8]  = fmaxf(m[8],  fmaxf(lo16f(va2.x), lo16f(vb2.x)));
                m[9]  = fmaxf(m[9],  fmaxf(hi16f(va2.x), hi16f(vb2.x)));
                m[10] = fmaxf(m[10], fmaxf(lo16f(va2.y), lo16f(vb2.y)));
                m[11] = fmaxf(m[11], fmaxf(hi16f(va2.y), hi16f(vb2.y)));
            }
        }

        // own row from LDS (same swizzle formula as the MFMA read side)
        int omsk = (ln & 15) << 2;
#pragma unroll
        for (int j = 0; j < 3; j++) {
            int qa = r + 8 * j;            // chunk 0..23
            uint2 o = *(const uint2*)&A_lds[ln * 200 + ((4 * qa) ^ omsk)];
            uint2 p;
            p.x = pack2_bf16(m[4 * j + 0] - lo16f(o.x), m[4 * j + 1] - hi16f(o.x));
            p.y = pack2_bf16(m[4 * j + 2] - lo16f(o.y), m[4 * j + 3] - hi16f(o.y));
            *(uint2*)&A_lds[ln * 200 + ((96 + 4 * qa) ^ omsk)] = p;
        }
    }
    __syncthreads();

    // ---- phase 2: MFMA. wave w: tm = w>>1, th = w&1.
    int w = tid >> 6, l = tid & 63;
    int tm = w >> 1, th = w & 1;

    float bcr[3];
#pragma unroll
    for (int j = 0; j < 3; j++) bcr[j] = bc[(th * 3 + j) * 16 + (l & 15)];

    f32x4 acc[3];
#pragma unroll
    for (int j = 0; j < 3; j++) acc[j] = (f32x4){0.f, 0.f, 0.f, 0.f};

    const uint4* wp4 = (const uint4*)Wp;
    int g = l >> 4;
    int msk = (l & 15) << 2;
    int abase = (tm * 16 + (l & 15)) * 200;

#pragma unroll
    for (int ks = 0; ks < 6; ks++) {
        FragU bfrag[3];
#pragma unroll
        for (int j = 0; j < 3; j++) {
            uint4 u = wp4[(ks * 6 + th * 3 + j) * 64 + l];
            bfrag[j].u[0] = u.x; bfrag[j].u[1] = u.y;
            bfrag[j].u[2] = u.z; bfrag[j].u[3] = u.w;
        }
        int k1 = ks * 32 + 4 * g;
        uint2 lo = *(const uint2*)&A_lds[abase + (k1 ^ msk)];
        uint2 hi = *(const uint2*)&A_lds[abase + ((k1 + 16) ^ msk)];
        FragU afrag;
        afrag.u[0] = lo.x; afrag.u[1] = lo.y;
        afrag.u[2] = hi.x; afrag.u[3] = hi.y;
#pragma unroll
        for (int j = 0; j < 3; j++)
            acc[j] = __builtin_amdgcn_mfma_f32_16x16x32_bf16(
                afrag.v, bfrag[j].v, acc[j], 0, 0, 0);
    }

    // ---- epilogue: o = (th*3+j)*16+(l&15), n = n0 + tm*16 + (l>>4)*4 + reg
    int nl = n0 + tm * 16 + ((l >> 4) << 2);
#pragma unroll
    for (int j = 0; j < 3; j++) {
        int o = (th * 3 + j) * 16 + (l & 15);
        float4 v;
        v.x = fmaxf(acc[j][0] + bcr[j], 0.0f);
        v.y = fmaxf(acc[j][1] + bcr[j], 0.0f);
        v.z = fmaxf(acc[j][2] + bcr[j], 0.0f);
        v.w = fmaxf(acc[j][3] + bcr[j], 0.0f);
        *(float4*)(out + ((size_t)b * C_ + o) * N_ + nl) = v;
    }
}

// ---------------------------------------------------------------------------
extern "C" void kernel_launch(void* const* d_in, const int* in_sizes, int n_in,
                              void* d_out, int out_size, void* d_ws, size_t ws_size,
                              hipStream_t stream) {
    const float* x   = (const float*)d_in[0];
    const int*   ei  = (const int*)d_in[1];     // [2, E] int32; row1 = src
    const float* Wc  = (const float*)d_in[2];   // [96, 192] interleaved
    const float* bc  = (const float*)d_in[3];   // [96]
    float* out = (float*)d_out;

    const int* src = ei + E_;

    // ws layout: feats bf16 [BN*96] | Wp bf16 [36*64*8]
    ushort* feats_bf = (ushort*)d_ws;
    ushort* Wp       = (ushort*)((char*)d_ws + (size_t)BN_ * C_ * 2);

    transpose_pack_k<<<1033, 256, 0, stream>>>(x, feats_bf, Wc, Wp);

    gconv_k<<<BN_ / 64, 512, 0, stream>>>(feats_bf, src, Wp, bc, out);
}